// Round 1
// baseline (15725.317 us; speedup 1.0000x reference)
//
#include <hip/hip_runtime.h>
#include <math.h>

#define BB 4
#define NF 128
#define CS 192
#define CH 96
#define H1 64
#define W1 64
#define H2 128
#define W2 128
#define P1 (H1*W1)
#define P2 (H2*W2)
#define EPSV 1e-5f
#define DTV 0.25f

__device__ __forceinline__ float softplus_f(float x) {
    return fmaxf(x, 0.0f) + log1pf(expf(-fabsf(x)));
}

// per-(b,c) mean & rstd over HW elements. grid = B*C, block = 256
__global__ __launch_bounds__(256) void meanvar_kernel(const float* __restrict__ x,
                                                      float* __restrict__ mv, int HW) {
    int bc = blockIdx.x;
    const float* p = x + (size_t)bc * HW;
    float s = 0.f, s2 = 0.f;
    for (int i = threadIdx.x; i < HW; i += 256) {
        float v = p[i];
        s += v; s2 += v * v;
    }
    __shared__ float sh[512];
    sh[threadIdx.x] = s; sh[256 + threadIdx.x] = s2;
    __syncthreads();
    for (int o = 128; o > 0; o >>= 1) {
        if (threadIdx.x < o) {
            sh[threadIdx.x] += sh[threadIdx.x + o];
            sh[256 + threadIdx.x] += sh[256 + threadIdx.x + o];
        }
        __syncthreads();
    }
    if (threadIdx.x == 0) {
        float m = sh[0] / (float)HW;
        float var = sh[256] / (float)HW - m * m;
        mv[2 * bc]     = m;
        mv[2 * bc + 1] = rsqrtf(var + EPSV);
    }
}

#define CI_CHUNK 16
#define CO_TILE 16

// direct 3x3 SAME conv, instance-norm fused into staging, softplus+bias epilogue.
// grid: (W/16, H/16, B * Cout/CO_TILE), block 256 (16x16 pixels)
__global__ __launch_bounds__(256) void conv3x3_kernel(
    const float* __restrict__ in, const float* __restrict__ mv,
    const float* __restrict__ w, const float* __restrict__ bias,
    float* __restrict__ out,
    int Cin, int H, int W, int outC, int outC0)
{
    __shared__ float tile[CI_CHUNK][324];   // 18x18 halo tile per cin
    int tx = threadIdx.x & 15, ty = threadIdx.x >> 4;
    int x0 = blockIdx.x * 16, y0 = blockIdx.y * 16;
    int nCo = gridDim.z / BB;
    int b = blockIdx.z / nCo;
    int co0 = (blockIdx.z % nCo) * CO_TILE;
    const float* inb = in + (size_t)b * Cin * H * W;

    float acc[CO_TILE];
#pragma unroll
    for (int i = 0; i < CO_TILE; i++) acc[i] = 0.f;

    for (int ci0 = 0; ci0 < Cin; ci0 += CI_CHUNK) {
        __syncthreads();
        for (int e = threadIdx.x; e < CI_CHUNK * 324; e += 256) {
            int ci = e / 324, r = e - ci * 324;
            int yy = r / 18, xx = r - yy * 18;
            int gy = y0 + yy - 1, gx = x0 + xx - 1;
            float v = 0.f;
            if (gy >= 0 && gy < H && gx >= 0 && gx < W) {
                v = inb[(size_t)(ci0 + ci) * H * W + gy * W + gx];
                float m  = mv[2 * (b * Cin + ci0 + ci)];
                float rs = mv[2 * (b * Cin + ci0 + ci) + 1];
                v = (v - m) * rs;
            }
            tile[ci][r] = v;
        }
        __syncthreads();
        for (int ci = 0; ci < CI_CHUNK; ci++) {
            float t[9];
#pragma unroll
            for (int dy = 0; dy < 3; dy++)
#pragma unroll
                for (int dx = 0; dx < 3; dx++)
                    t[dy * 3 + dx] = tile[ci][(ty + dy) * 18 + tx + dx];
            const float* wp = w + ((size_t)co0 * Cin + (ci0 + ci)) * 9;
#pragma unroll
            for (int co = 0; co < CO_TILE; co++) {
#pragma unroll
                for (int k = 0; k < 9; k++)
                    acc[co] = fmaf(t[k], wp[(size_t)co * Cin * 9 + k], acc[co]);
            }
        }
    }
    int oy = y0 + ty, ox = x0 + tx;
    float* outb = out + ((size_t)b * outC + outC0) * H * W;
#pragma unroll
    for (int co = 0; co < CO_TILE; co++) {
        float v = softplus_f(acc[co] + bias[co0 + co]);
        outb[(size_t)co * H * W + (size_t)(co0 == 0 ? 0 : 0)] = v; // placeholder avoided below
    }
    // NOTE: the line above is rewritten properly here (kept single store path):
}

// (the stray placeholder above is unreachable-free: we re-implement the epilogue
//  in a corrected kernel below — see conv3x3_kernel_fixed)

__global__ __launch_bounds__(256) void conv3x3_kernel_fixed(
    const float* __restrict__ in, const float* __restrict__ mv,
    const float* __restrict__ w, const float* __restrict__ bias,
    float* __restrict__ out,
    int Cin, int H, int W, int outC, int outC0)
{
    __shared__ float tile[CI_CHUNK][324];
    int tx = threadIdx.x & 15, ty = threadIdx.x >> 4;
    int x0 = blockIdx.x * 16, y0 = blockIdx.y * 16;
    int nCo = gridDim.z / BB;
    int b = blockIdx.z / nCo;
    int co0 = (blockIdx.z % nCo) * CO_TILE;
    const float* inb = in + (size_t)b * Cin * H * W;

    float acc[CO_TILE];
#pragma unroll
    for (int i = 0; i < CO_TILE; i++) acc[i] = 0.f;

    for (int ci0 = 0; ci0 < Cin; ci0 += CI_CHUNK) {
        __syncthreads();
        for (int e = threadIdx.x; e < CI_CHUNK * 324; e += 256) {
            int ci = e / 324, r = e - ci * 324;
            int yy = r / 18, xx = r - yy * 18;
            int gy = y0 + yy - 1, gx = x0 + xx - 1;
            float v = 0.f;
            if (gy >= 0 && gy < H && gx >= 0 && gx < W) {
                v = inb[(size_t)(ci0 + ci) * H * W + gy * W + gx];
                float m  = mv[2 * (b * Cin + ci0 + ci)];
                float rs = mv[2 * (b * Cin + ci0 + ci) + 1];
                v = (v - m) * rs;
            }
            tile[ci][r] = v;
        }
        __syncthreads();
        for (int ci = 0; ci < CI_CHUNK; ci++) {
            float t[9];
#pragma unroll
            for (int dy = 0; dy < 3; dy++)
#pragma unroll
                for (int dx = 0; dx < 3; dx++)
                    t[dy * 3 + dx] = tile[ci][(ty + dy) * 18 + tx + dx];
            const float* wp = w + ((size_t)co0 * Cin + (ci0 + ci)) * 9;
#pragma unroll
            for (int co = 0; co < CO_TILE; co++) {
#pragma unroll
                for (int k = 0; k < 9; k++)
                    acc[co] = fmaf(t[k], wp[(size_t)co * Cin * 9 + k], acc[co]);
            }
        }
    }
    int oy = y0 + ty, ox = x0 + tx;
    float* outb = out + ((size_t)b * outC + outC0) * H * W + (size_t)oy * W + ox;
#pragma unroll
    for (int co = 0; co < CO_TILE; co++) {
        float v = softplus_f(acc[co] + bias[co0 + co]);
        outb[(size_t)(co0 + co) * H * W] = v;
    }
}

// bilinear 2x upsample of concat(x, v0): out ycat (B,256,128,128)
__global__ __launch_bounds__(256) void upsample_kernel(const float* __restrict__ x,
                                                       const float* __restrict__ v0,
                                                       float* __restrict__ ycat) {
    size_t idx = (size_t)blockIdx.x * 256 + threadIdx.x;   // B*256*P2
    int oxy = (int)(idx & (size_t)(P2 - 1));
    int ox = oxy & 127, oy = oxy >> 7;
    int cbc = (int)(idx >> 14);
    int c = cbc & 255, b = cbc >> 8;
    const float* src = (c < 128 ? x : v0) + (size_t)(b * 128 + (c & 127)) * P1;
    int my = oy >> 1, mx = ox >> 1;
    int iy0 = (oy & 1) ? my : my - 1;
    float wy0 = (oy & 1) ? 0.75f : 0.25f;
    int ix0 = (ox & 1) ? mx : mx - 1;
    float wx0 = (ox & 1) ? 0.75f : 0.25f;
    int iy1 = min(iy0 + 1, H1 - 1); iy0 = max(iy0, 0);
    int ix1 = min(ix0 + 1, W1 - 1); ix0 = max(ix0, 0);
    float wy1 = 1.f - wy0, wx1 = 1.f - wx0;
    float v = wy0 * (wx0 * src[iy0 * W1 + ix0] + wx1 * src[iy0 * W1 + ix1])
            + wy1 * (wx0 * src[iy1 * W1 + ix0] + wx1 * src[iy1 * W1 + ix1]);
    ycat[idx] = v;
}

// 1x1 conv 384->192 with softplus. grid (P2/64, 192/16, B), block 256
__global__ __launch_bounds__(256) void conv1x1_kernel(
    const float* __restrict__ ycat, const float* __restrict__ skip,
    const float* __restrict__ w, const float* __restrict__ bias,
    float* __restrict__ out)
{
    __shared__ float lds[64][64];
    int px = threadIdx.x & 63;
    int cog = threadIdx.x >> 6;
    int p0 = blockIdx.x * 64;
    int co0 = blockIdx.y * 16;
    int b = blockIdx.z;
    float acc[4] = {0.f, 0.f, 0.f, 0.f};
    for (int ci0 = 0; ci0 < 384; ci0 += 64) {
        __syncthreads();
        for (int e = threadIdx.x; e < 64 * 64; e += 256) {
            int ci = ci0 + (e >> 6);
            int pp = p0 + (e & 63);
            float v = (ci < 256) ? ycat[((size_t)b * 256 + ci) * P2 + pp]
                                 : skip[((size_t)b * 128 + (ci - 256)) * P2 + pp];
            lds[e >> 6][e & 63] = v;
        }
        __syncthreads();
        for (int ci = 0; ci < 64; ci++) {
            float t = lds[ci][px];
#pragma unroll
            for (int j = 0; j < 4; j++)
                acc[j] = fmaf(t, w[(size_t)(co0 + cog * 4 + j) * 384 + ci0 + ci], acc[j]);
        }
    }
#pragma unroll
    for (int j = 0; j < 4; j++) {
        int co = co0 + cog * 4 + j;
        out[((size_t)b * CS + co) * P2 + p0 + px] = softplus_f(acc[j] + bias[co]);
    }
}

// K[:, 0:96] = Y[:, 96:192]  (float4 units)
__global__ __launch_bounds__(256) void copyv_kernel(const float* __restrict__ Y,
                                                    float* __restrict__ K, int n4) {
    int i = blockIdx.x * 256 + threadIdx.x;
    if (i >= n4) return;
    int per_b = CH * P2 / 4;
    int b = i / per_b, r = i - b * per_b;
    ((float4*)K)[(size_t)b * (CS * P2 / 4) + r] =
        ((const float4*)Y)[(size_t)b * (CS * P2 / 4) + per_b + r];
}

// ACC = accA*ACC + accB*K ; T = S + tC*K
__global__ __launch_bounds__(256) void combine_kernel(const float* __restrict__ S,
                                                      const float* __restrict__ K,
                                                      float* __restrict__ ACC,
                                                      float* __restrict__ T,
                                                      float accA, float accB, float tC, int N4) {
    int i = blockIdx.x * 256 + threadIdx.x;
    if (i >= N4) return;
    float4 s = ((const float4*)S)[i];
    float4 k = ((const float4*)K)[i];
    float4 a;
    if (accA == 0.f) {
        a.x = accB * k.x; a.y = accB * k.y; a.z = accB * k.z; a.w = accB * k.w;
    } else {
        a = ((const float4*)ACC)[i];
        a.x += accB * k.x; a.y += accB * k.y; a.z += accB * k.z; a.w += accB * k.w;
    }
    ((float4*)ACC)[i] = a;
    float4 t;
    t.x = s.x + tC * k.x; t.y = s.y + tC * k.y; t.z = s.z + tC * k.z; t.w = s.w + tC * k.w;
    ((float4*)T)[i] = t;
}

// S += DT/6 * (ACC + K)
__global__ __launch_bounds__(256) void final_kernel(float* __restrict__ S,
                                                    const float* __restrict__ ACC,
                                                    const float* __restrict__ K, int N4) {
    int i = blockIdx.x * 256 + threadIdx.x;
    if (i >= N4) return;
    float4 s = ((float4*)S)[i];
    float4 a = ((const float4*)ACC)[i];
    float4 k = ((const float4*)K)[i];
    const float c = DTV / 6.0f;
    s.x += c * (a.x + k.x); s.y += c * (a.y + k.y);
    s.z += c * (a.z + k.z); s.w += c * (a.w + k.w);
    ((float4*)S)[i] = s;
}

extern "C" void kernel_launch(void* const* d_in, const int* in_sizes, int n_in,
                              void* d_out, int out_size, void* d_ws, size_t ws_size,
                              hipStream_t stream) {
    (void)in_sizes; (void)n_in; (void)out_size; (void)ws_size;
    const float* x    = (const float*)d_in[0];
    const float* skip = (const float*)d_in[1];
    const float* iv_w = (const float*)d_in[2];
    const float* iv_b = (const float*)d_in[3];
    const float* up_w = (const float*)d_in[4];
    const float* up_b = (const float*)d_in[5];
    const float* f1_w = (const float*)d_in[6];
    const float* f1_b = (const float*)d_in[7];
    const float* f2_w = (const float*)d_in[8];
    const float* f2_b = (const float*)d_in[9];

    float* S = (float*)d_out;                    // B x 192 x 128 x 128 (state, in-place)
    float* ws = (float*)d_ws;
    const size_t NS = (size_t)BB * CS * P2;      // 12,582,912
    float* T    = ws;
    float* ACC  = T + NS;
    float* K    = ACC + NS;
    float* U    = K + NS;                        // B x 96 x P2
    float* MV   = U + (size_t)BB * CH * P2;      // small
    float* YCAT = T;                             // alias over T+ACC (16.8M <= 25.2M)
    float* V0   = K;                             // alias over K (2.1M <= 12.6M)

    const int N4  = (int)(NS / 4);               // 3,145,728
    const int nb4 = N4 / 256;                    // 12288
    const int nK4 = (int)((size_t)BB * CH * P2 / 4); // 1,572,864
    const int nbK = nK4 / 256;                   // 6144

    // ---- Phase A ----
    meanvar_kernel<<<BB * NF, 256, 0, stream>>>(x, MV, P1);
    conv3x3_kernel_fixed<<<dim3(W1 / 16, H1 / 16, BB * (NF / CO_TILE)), 256, 0, stream>>>(
        x, MV, iv_w, iv_b, V0, NF, H1, W1, NF, 0);
    upsample_kernel<<<(BB * 256 * P2) / 256, 256, 0, stream>>>(x, V0, YCAT);
    conv1x1_kernel<<<dim3(P2 / 64, CS / 16, BB), 256, 0, stream>>>(YCAT, skip, up_w, up_b, S);

    // ---- RK4 ODE ----
    auto feval = [&](const float* Y) {
        meanvar_kernel<<<BB * CS, 256, 0, stream>>>(Y, MV, P2);
        conv3x3_kernel_fixed<<<dim3(W2 / 16, H2 / 16, BB * (CH / CO_TILE)), 256, 0, stream>>>(
            Y, MV, f1_w, f1_b, U, CS, H2, W2, CH, 0);
        meanvar_kernel<<<BB * CH, 256, 0, stream>>>(U, MV, P2);
        conv3x3_kernel_fixed<<<dim3(W2 / 16, H2 / 16, BB * (CH / CO_TILE)), 256, 0, stream>>>(
            U, MV, f2_w, f2_b, K, CH, H2, W2, CS, CH);
        copyv_kernel<<<nbK, 256, 0, stream>>>(Y, K, nK4);
    };

    for (int step = 0; step < 4; step++) {
        feval(S);
        combine_kernel<<<nb4, 256, 0, stream>>>(S, K, ACC, T, 0.f, 1.f, 0.5f * DTV, N4);
        feval(T);
        combine_kernel<<<nb4, 256, 0, stream>>>(S, K, ACC, T, 1.f, 2.f, 0.5f * DTV, N4);
        feval(T);
        combine_kernel<<<nb4, 256, 0, stream>>>(S, K, ACC, T, 1.f, 2.f, DTV, N4);
        feval(T);
        final_kernel<<<nb4, 256, 0, stream>>>(S, ACC, K, N4);
    }
}

// Round 2
// 4632.965 us; speedup vs baseline: 3.3942x; 3.3942x over previous
//
#include <hip/hip_runtime.h>
#include <math.h>

#define BB 4
#define NF 128
#define CS 192
#define CH 96
#define H1 64
#define W1 64
#define H2 128
#define W2 128
#define P1 (H1*W1)
#define P2 (H2*W2)
#define EPSV 1e-5f
#define DTV 0.25f

typedef __attribute__((ext_vector_type(8))) short short8;
typedef __attribute__((ext_vector_type(4))) float f32x4;

__device__ __forceinline__ float softplus_f(float x) {
    return fmaxf(x, 0.0f) + log1pf(expf(-fabsf(x)));
}
__device__ __forceinline__ unsigned f2bf(float f) {
    unsigned u = __float_as_uint(f);
    return (u + 0x7FFFu + ((u >> 16) & 1u)) >> 16;   // RNE to bf16
}

// per-(b,c) mean & rstd over HW elements. grid = B*C, block = 256
__global__ __launch_bounds__(256) void meanvar_kernel(const float* __restrict__ x,
                                                      float* __restrict__ mv, int HW) {
    int bc = blockIdx.x;
    const float* p = x + (size_t)bc * HW;
    float s = 0.f, s2 = 0.f;
    for (int i = threadIdx.x; i < HW; i += 256) {
        float v = p[i];
        s += v; s2 += v * v;
    }
    __shared__ float sh[512];
    sh[threadIdx.x] = s; sh[256 + threadIdx.x] = s2;
    __syncthreads();
    for (int o = 128; o > 0; o >>= 1) {
        if (threadIdx.x < o) {
            sh[threadIdx.x] += sh[threadIdx.x + o];
            sh[256 + threadIdx.x] += sh[256 + threadIdx.x + o];
        }
        __syncthreads();
    }
    if (threadIdx.x == 0) {
        float m = sh[0] / (float)HW;
        float var = sh[256] / (float)HW - m * m;
        mv[2 * bc]     = m;
        mv[2 * bc + 1] = rsqrtf(var + EPSV);
    }
}

// repack w[co][ci][3][3] fp32 -> wq[tap][co][ci] bf16
__global__ __launch_bounds__(256) void repack_w_kernel(const float* __restrict__ w,
                                                       short* __restrict__ wq,
                                                       int Cout, int Cin) {
    int idx = blockIdx.x * 256 + threadIdx.x;
    int total = Cout * Cin * 9;
    if (idx >= total) return;
    int tap = idx % 9;
    int t = idx / 9;
    int ci = t % Cin, co = t / Cin;
    wq[((size_t)tap * Cout + co) * Cin + ci] = (short)f2bf(w[idx]);
}

// 3x3 SAME conv, instance-norm fused into bf16 LDS staging, MFMA 16x16x32 bf16,
// softplus+bias epilogue. Output tile 16 wide x 8 tall; 4 waves (2 rows each);
// NCG co-groups of 16 per block. grid (W/16, H/8, B*coblk).
template<int NCG>
__global__ __launch_bounds__(256) void conv3x3_mfma(
    const float* __restrict__ in, const float* __restrict__ mv,
    const short* __restrict__ wq, const float* __restrict__ bias,
    float* __restrict__ out,
    int Cin, int CoutT, int H, int W, int outC, int outCoff, int coblk)
{
    __shared__ short xt[180 * 40];     // 18x10 halo px, 80B/px (32 bf16 + pad)
    const int tid = threadIdx.x;
    const int wave = tid >> 6, lane = tid & 63;
    const int lx = lane & 15, q = lane >> 4;
    const int x0 = blockIdx.x * 16, y0 = blockIdx.y * 8;
    const int b = blockIdx.z / coblk;
    const int co_base = (blockIdx.z % coblk) * (NCG * 16);
    const int HWp = H * W;
    const float* inb = in + (size_t)b * Cin * HWp;
    const float* mvb = mv + 2 * b * Cin;

    f32x4 acc[2][NCG];
#pragma unroll
    for (int rr = 0; rr < 2; rr++)
#pragma unroll
        for (int cg = 0; cg < NCG; cg++) acc[rr][cg] = (f32x4)(0.f);

    for (int ci0 = 0; ci0 < Cin; ci0 += 32) {
        __syncthreads();
        // stage 32 ci planes of the halo tile, normalized, as bf16 [px][ci]
        for (int e = tid; e < 180 * 8; e += 256) {
            int px = e % 180;
            int cq = e / 180;                    // ci-quad (4 channels)
            int yy = px / 18, xx = px % 18;
            int gy = y0 + yy - 1, gx = x0 + xx - 1;
            int ci = ci0 + cq * 4;
            unsigned p0 = 0, p1 = 0;
            if (gy >= 0 && gy < H && gx >= 0 && gx < W) {
                const float* g = inb + (size_t)ci * HWp + gy * W + gx;
                const float* m = mvb + 2 * ci;
                float v0 = (g[0]                - m[0]) * m[1];
                float v1 = (g[(size_t)HWp]      - m[2]) * m[3];
                float v2 = (g[(size_t)2 * HWp]  - m[4]) * m[5];
                float v3 = (g[(size_t)3 * HWp]  - m[6]) * m[7];
                p0 = f2bf(v0) | (f2bf(v1) << 16);
                p1 = f2bf(v2) | (f2bf(v3) << 16);
            }
            *(int2*)(&xt[px * 40 + cq * 4]) = make_int2((int)p0, (int)p1);
        }
        __syncthreads();

        const short* wl = wq + (size_t)(co_base + lx) * Cin + ci0 + q * 8;
#pragma unroll
        for (int tap = 0; tap < 9; tap++) {
            const int dy = tap / 3, dx = tap % 3;
            short8 a[NCG];
#pragma unroll
            for (int cg = 0; cg < NCG; cg++)
                a[cg] = *(const short8*)(wl + ((size_t)tap * CoutT + cg * 16) * Cin);
#pragma unroll
            for (int rr = 0; rr < 2; rr++) {
                int row = wave * 2 + rr;
                short8 bfr = *(const short8*)(&xt[((row + dy) * 18 + lx + dx) * 40 + q * 8]);
#pragma unroll
                for (int cg = 0; cg < NCG; cg++)
                    acc[rr][cg] = __builtin_amdgcn_mfma_f32_16x16x32_bf16(
                        a[cg], bfr, acc[rr][cg], 0, 0, 0);
            }
        }
    }

    float* outb = out + ((size_t)b * outC + outCoff + co_base) * HWp;
#pragma unroll
    for (int rr = 0; rr < 2; rr++) {
        int y = y0 + wave * 2 + rr;
#pragma unroll
        for (int cg = 0; cg < NCG; cg++) {
#pragma unroll
            for (int r = 0; r < 4; r++) {
                int co = cg * 16 + q * 4 + r;
                float v = softplus_f(acc[rr][cg][r] + bias[co_base + co]);
                outb[(size_t)co * HWp + y * W + x0 + lx] = v;
            }
        }
    }
}

// bilinear 2x upsample of concat(x, v0): out ycat (B,256,128,128)
__global__ __launch_bounds__(256) void upsample_kernel(const float* __restrict__ x,
                                                       const float* __restrict__ v0,
                                                       float* __restrict__ ycat) {
    size_t idx = (size_t)blockIdx.x * 256 + threadIdx.x;
    int oxy = (int)(idx & (size_t)(P2 - 1));
    int ox = oxy & 127, oy = oxy >> 7;
    int cbc = (int)(idx >> 14);
    int c = cbc & 255, b = cbc >> 8;
    const float* src = (c < 128 ? x : v0) + (size_t)(b * 128 + (c & 127)) * P1;
    int my = oy >> 1, mx = ox >> 1;
    int iy0 = (oy & 1) ? my : my - 1;
    float wy0 = (oy & 1) ? 0.75f : 0.25f;
    int ix0 = (ox & 1) ? mx : mx - 1;
    float wx0 = (ox & 1) ? 0.75f : 0.25f;
    int iy1 = min(iy0 + 1, H1 - 1); iy0 = max(iy0, 0);
    int ix1 = min(ix0 + 1, W1 - 1); ix0 = max(ix0, 0);
    float wy1 = 1.f - wy0, wx1 = 1.f - wx0;
    float v = wy0 * (wx0 * src[iy0 * W1 + ix0] + wx1 * src[iy0 * W1 + ix1])
            + wy1 * (wx0 * src[iy1 * W1 + ix0] + wx1 * src[iy1 * W1 + ix1]);
    ycat[idx] = v;
}

// 1x1 conv 384->192 with softplus. grid (P2/64, 192/16, B), block 256
__global__ __launch_bounds__(256) void conv1x1_kernel(
    const float* __restrict__ ycat, const float* __restrict__ skip,
    const float* __restrict__ w, const float* __restrict__ bias,
    float* __restrict__ out)
{
    __shared__ float lds[64][64];
    int px = threadIdx.x & 63;
    int cog = threadIdx.x >> 6;
    int p0 = blockIdx.x * 64;
    int co0 = blockIdx.y * 16;
    int b = blockIdx.z;
    float acc[4] = {0.f, 0.f, 0.f, 0.f};
    for (int ci0 = 0; ci0 < 384; ci0 += 64) {
        __syncthreads();
        for (int e = threadIdx.x; e < 64 * 64; e += 256) {
            int ci = ci0 + (e >> 6);
            int pp = p0 + (e & 63);
            float v = (ci < 256) ? ycat[((size_t)b * 256 + ci) * P2 + pp]
                                 : skip[((size_t)b * 128 + (ci - 256)) * P2 + pp];
            lds[e >> 6][e & 63] = v;
        }
        __syncthreads();
        for (int ci = 0; ci < 64; ci++) {
            float t = lds[ci][px];
#pragma unroll
            for (int j = 0; j < 4; j++)
                acc[j] = fmaf(t, w[(size_t)(co0 + cog * 4 + j) * 384 + ci0 + ci], acc[j]);
        }
    }
#pragma unroll
    for (int j = 0; j < 4; j++) {
        int co = co0 + cog * 4 + j;
        out[((size_t)b * CS + co) * P2 + p0 + px] = softplus_f(acc[j] + bias[co]);
    }
}

// K[:, 0:96] = Y[:, 96:192]  (float4 units)
__global__ __launch_bounds__(256) void copyv_kernel(const float* __restrict__ Y,
                                                    float* __restrict__ K, int n4) {
    int i = blockIdx.x * 256 + threadIdx.x;
    if (i >= n4) return;
    int per_b = CH * P2 / 4;
    int b = i / per_b, r = i - b * per_b;
    ((float4*)K)[(size_t)b * (CS * P2 / 4) + r] =
        ((const float4*)Y)[(size_t)b * (CS * P2 / 4) + per_b + r];
}

// ACC = accA*ACC + accB*K ; T = S + tC*K
__global__ __launch_bounds__(256) void combine_kernel(const float* __restrict__ S,
                                                      const float* __restrict__ K,
                                                      float* __restrict__ ACC,
                                                      float* __restrict__ T,
                                                      float accA, float accB, float tC, int N4) {
    int i = blockIdx.x * 256 + threadIdx.x;
    if (i >= N4) return;
    float4 s = ((const float4*)S)[i];
    float4 k = ((const float4*)K)[i];
    float4 a;
    if (accA == 0.f) {
        a.x = accB * k.x; a.y = accB * k.y; a.z = accB * k.z; a.w = accB * k.w;
    } else {
        a = ((const float4*)ACC)[i];
        a.x += accB * k.x; a.y += accB * k.y; a.z += accB * k.z; a.w += accB * k.w;
    }
    ((float4*)ACC)[i] = a;
    float4 t;
    t.x = s.x + tC * k.x; t.y = s.y + tC * k.y; t.z = s.z + tC * k.z; t.w = s.w + tC * k.w;
    ((float4*)T)[i] = t;
}

// S += DT/6 * (ACC + K)
__global__ __launch_bounds__(256) void final_kernel(float* __restrict__ S,
                                                    const float* __restrict__ ACC,
                                                    const float* __restrict__ K, int N4) {
    int i = blockIdx.x * 256 + threadIdx.x;
    if (i >= N4) return;
    float4 s = ((float4*)S)[i];
    float4 a = ((const float4*)ACC)[i];
    float4 k = ((const float4*)K)[i];
    const float c = DTV / 6.0f;
    s.x += c * (a.x + k.x); s.y += c * (a.y + k.y);
    s.z += c * (a.z + k.z); s.w += c * (a.w + k.w);
    ((float4*)S)[i] = s;
}

extern "C" void kernel_launch(void* const* d_in, const int* in_sizes, int n_in,
                              void* d_out, int out_size, void* d_ws, size_t ws_size,
                              hipStream_t stream) {
    (void)in_sizes; (void)n_in; (void)out_size; (void)ws_size;
    const float* x    = (const float*)d_in[0];
    const float* skip = (const float*)d_in[1];
    const float* iv_w = (const float*)d_in[2];
    const float* iv_b = (const float*)d_in[3];
    const float* up_w = (const float*)d_in[4];
    const float* up_b = (const float*)d_in[5];
    const float* f1_w = (const float*)d_in[6];
    const float* f1_b = (const float*)d_in[7];
    const float* f2_w = (const float*)d_in[8];
    const float* f2_b = (const float*)d_in[9];

    float* S = (float*)d_out;                    // B x 192 x 128 x 128
    float* ws = (float*)d_ws;
    const size_t NS = (size_t)BB * CS * P2;      // 12,582,912
    float* T    = ws;
    float* ACC  = T + NS;
    float* K    = ACC + NS;
    float* U    = K + NS;                        // B x 96 x P2
    float* MV   = U + (size_t)BB * CH * P2;      // <= 1536 used
    short* IVQ  = (short*)(MV + 2048);           // bf16 packed weights
    short* F1Q  = IVQ + (size_t)9 * NF * NF;     // 147456 shorts
    short* F2Q  = F1Q + (size_t)9 * CH * CS;     // 165888 shorts
    float* YCAT = T;                             // alias over T+ACC (phase A only)
    float* V0   = K;                             // alias over K (phase A only)

    const int N4  = (int)(NS / 4);
    const int nb4 = N4 / 256;
    const int nK4 = (int)((size_t)BB * CH * P2 / 4);
    const int nbK = nK4 / 256;

    // ---- weight repack (cheap, every call) ----
    repack_w_kernel<<<(NF * NF * 9 + 255) / 256, 256, 0, stream>>>(iv_w, IVQ, NF, NF);
    repack_w_kernel<<<(CH * CS * 9 + 255) / 256, 256, 0, stream>>>(f1_w, F1Q, CH, CS);
    repack_w_kernel<<<(CH * CH * 9 + 255) / 256, 256, 0, stream>>>(f2_w, F2Q, CH, CH);

    // ---- Phase A ----
    meanvar_kernel<<<BB * NF, 256, 0, stream>>>(x, MV, P1);
    conv3x3_mfma<4><<<dim3(W1 / 16, H1 / 8, BB * 2), 256, 0, stream>>>(
        x, MV, IVQ, iv_b, V0, NF, NF, H1, W1, NF, 0, 2);
    upsample_kernel<<<(BB * 256 * P2) / 256, 256, 0, stream>>>(x, V0, YCAT);
    conv1x1_kernel<<<dim3(P2 / 64, CS / 16, BB), 256, 0, stream>>>(YCAT, skip, up_w, up_b, S);

    // ---- RK4 ODE ----
    auto feval = [&](const float* Y) {
        meanvar_kernel<<<BB * CS, 256, 0, stream>>>(Y, MV, P2);
        conv3x3_mfma<6><<<dim3(W2 / 16, H2 / 8, BB), 256, 0, stream>>>(
            Y, MV, F1Q, f1_b, U, CS, CH, H2, W2, CH, 0, 1);
        meanvar_kernel<<<BB * CH, 256, 0, stream>>>(U, MV, P2);
        conv3x3_mfma<6><<<dim3(W2 / 16, H2 / 8, BB), 256, 0, stream>>>(
            U, MV, F2Q, f2_b, K, CH, CH, H2, W2, CS, CH, 1);
        copyv_kernel<<<nbK, 256, 0, stream>>>(Y, K, nK4);
    };

    for (int step = 0; step < 4; step++) {
        feval(S);
        combine_kernel<<<nb4, 256, 0, stream>>>(S, K, ACC, T, 0.f, 1.f, 0.5f * DTV, N4);
        feval(T);
        combine_kernel<<<nb4, 256, 0, stream>>>(S, K, ACC, T, 1.f, 2.f, 0.5f * DTV, N4);
        feval(T);
        combine_kernel<<<nb4, 256, 0, stream>>>(S, K, ACC, T, 1.f, 2.f, DTV, N4);
        feval(T);
        final_kernel<<<nb4, 256, 0, stream>>>(S, ACC, K, N4);
    }
}

// Round 3
// 3387.271 us; speedup vs baseline: 4.6425x; 1.3678x over previous
//
#include <hip/hip_runtime.h>
#include <math.h>

#define BB 4
#define NF 128
#define CS 192
#define CH 96
#define H1 64
#define W1 64
#define H2 128
#define W2 128
#define P1 (H1*W1)
#define P2 (H2*W2)
#define EPSV 1e-5f
#define DTV 0.25f

typedef __attribute__((ext_vector_type(8))) short short8;
typedef __attribute__((ext_vector_type(4))) float f32x4;

__device__ __forceinline__ float softplus_f(float x) {
    return fmaxf(x, 0.0f) + log1pf(expf(-fabsf(x)));
}
__device__ __forceinline__ unsigned f2bf(float f) {
    unsigned u = __float_as_uint(f);
    return (u + 0x7FFFu + ((u >> 16) & 1u)) >> 16;   // RNE to bf16
}

__global__ __launch_bounds__(256) void zero_kernel(float* __restrict__ p, int n) {
    int i = blockIdx.x * 256 + threadIdx.x;
    if (i < n) p[i] = 0.f;
}

// per-(b,c) raw (sum, sumsq) over HW. grid = B*C, block = 256
__global__ __launch_bounds__(256) void meanvar_raw_kernel(const float* __restrict__ x,
                                                          float* __restrict__ mv, int HW) {
    int bc = blockIdx.x;
    const float* p = x + (size_t)bc * HW;
    float s = 0.f, s2 = 0.f;
    for (int i = threadIdx.x; i < HW; i += 256) {
        float v = p[i];
        s += v; s2 += v * v;
    }
    __shared__ float sh[512];
    sh[threadIdx.x] = s; sh[256 + threadIdx.x] = s2;
    __syncthreads();
    for (int o = 128; o > 0; o >>= 1) {
        if (threadIdx.x < o) {
            sh[threadIdx.x] += sh[threadIdx.x + o];
            sh[256 + threadIdx.x] += sh[256 + threadIdx.x + o];
        }
        __syncthreads();
    }
    if (threadIdx.x == 0) {
        mv[2 * bc]     = sh[0];
        mv[2 * bc + 1] = sh[256];
    }
}

// repack w[co][ci][3][3] fp32 -> wq[tap][co][ci] bf16
__global__ __launch_bounds__(256) void repack_w_kernel(const float* __restrict__ w,
                                                       short* __restrict__ wq,
                                                       int Cout, int Cin) {
    int idx = blockIdx.x * 256 + threadIdx.x;
    int total = Cout * Cin * 9;
    if (idx >= total) return;
    int tap = idx % 9;
    int t = idx / 9;
    int ci = t % Cin, co = t / Cin;
    wq[((size_t)tap * Cout + co) * Cin + ci] = (short)f2bf(w[idx]);
}

// flat fp32 -> bf16 cast (1x1 weights already [co][ci])
__global__ __launch_bounds__(256) void repack_w1_kernel(const float* __restrict__ w,
                                                        short* __restrict__ wq, int n) {
    int i = blockIdx.x * 256 + threadIdx.x;
    if (i < n) wq[i] = (short)f2bf(w[i]);
}

// 3x3 SAME conv, instance-norm (from raw sums) fused into bf16 LDS staging,
// MFMA 16x16x32 bf16, softplus+bias epilogue; optional fused output channel-sums.
// grid (W/16, H/8, B*coblk), block 256.
template<int NCG, bool SUMS>
__global__ __launch_bounds__(256) void conv3x3_mfma(
    const float* __restrict__ in, const float* __restrict__ mvsums,
    const short* __restrict__ wq, const float* __restrict__ bias,
    float* __restrict__ out, float* __restrict__ osum,
    int Cin, int CoutT, int H, int W, int outC, int outCoff, int coblk)
{
    __shared__ short xt[180 * 40];     // 18x10 halo px, 80B/px (32 bf16 + pad)
    __shared__ float mvl[2 * CS];      // mean/rstd per input channel
    __shared__ float shs[2 * CH];      // per-co block sums (SUMS only)
    const int tid = threadIdx.x;
    const int wave = tid >> 6, lane = tid & 63;
    const int lx = lane & 15, q = lane >> 4;
    const int x0 = blockIdx.x * 16, y0 = blockIdx.y * 8;
    const int b = blockIdx.z / coblk;
    const int co_base = (blockIdx.z % coblk) * (NCG * 16);
    const int HWp = H * W;
    const float* inb = in + (size_t)b * Cin * HWp;

    const float invHW = 1.0f / (float)HWp;
    for (int c = tid; c < Cin; c += 256) {
        float s  = mvsums[(b * Cin + c) * 2];
        float s2 = mvsums[(b * Cin + c) * 2 + 1];
        float m  = s * invHW;
        float var = fmaxf(s2 * invHW - m * m, 0.f);
        mvl[2 * c]     = m;
        mvl[2 * c + 1] = rsqrtf(var + EPSV);
    }
    if (SUMS) for (int c = tid; c < 2 * CH; c += 256) shs[c] = 0.f;

    f32x4 acc[2][NCG];
#pragma unroll
    for (int rr = 0; rr < 2; rr++)
#pragma unroll
        for (int cg = 0; cg < NCG; cg++) acc[rr][cg] = (f32x4)(0.f);

    for (int ci0 = 0; ci0 < Cin; ci0 += 32) {
        __syncthreads();
        for (int e = tid; e < 180 * 8; e += 256) {
            int px = e % 180;
            int cq = e / 180;
            int yy = px / 18, xx = px % 18;
            int gy = y0 + yy - 1, gx = x0 + xx - 1;
            int ci = ci0 + cq * 4;
            unsigned p0 = 0, p1 = 0;
            if (gy >= 0 && gy < H && gx >= 0 && gx < W) {
                const float* g = inb + (size_t)ci * HWp + gy * W + gx;
                float v0 = (g[0]               - mvl[2*ci])   * mvl[2*ci+1];
                float v1 = (g[(size_t)HWp]     - mvl[2*ci+2]) * mvl[2*ci+3];
                float v2 = (g[(size_t)2*HWp]   - mvl[2*ci+4]) * mvl[2*ci+5];
                float v3 = (g[(size_t)3*HWp]   - mvl[2*ci+6]) * mvl[2*ci+7];
                p0 = f2bf(v0) | (f2bf(v1) << 16);
                p1 = f2bf(v2) | (f2bf(v3) << 16);
            }
            *(int2*)(&xt[px * 40 + cq * 4]) = make_int2((int)p0, (int)p1);
        }
        __syncthreads();

        const short* wl = wq + (size_t)(co_base + lx) * Cin + ci0 + q * 8;
#pragma unroll
        for (int tap = 0; tap < 9; tap++) {
            const int dy = tap / 3, dx = tap % 3;
            short8 a[NCG];
#pragma unroll
            for (int cg = 0; cg < NCG; cg++)
                a[cg] = *(const short8*)(wl + ((size_t)tap * CoutT + cg * 16) * Cin);
#pragma unroll
            for (int rr = 0; rr < 2; rr++) {
                int row = wave * 2 + rr;
                short8 bfr = *(const short8*)(&xt[((row + dy) * 18 + lx + dx) * 40 + q * 8]);
#pragma unroll
                for (int cg = 0; cg < NCG; cg++)
                    acc[rr][cg] = __builtin_amdgcn_mfma_f32_16x16x32_bf16(
                        a[cg], bfr, acc[rr][cg], 0, 0, 0);
            }
        }
    }

    float* outb = out + ((size_t)b * outC + outCoff + co_base) * HWp;
    float s1l[NCG][4], s2l[NCG][4];
    if (SUMS) {
#pragma unroll
        for (int cg = 0; cg < NCG; cg++)
#pragma unroll
            for (int r = 0; r < 4; r++) { s1l[cg][r] = 0.f; s2l[cg][r] = 0.f; }
    }
#pragma unroll
    for (int rr = 0; rr < 2; rr++) {
        int y = y0 + wave * 2 + rr;
#pragma unroll
        for (int cg = 0; cg < NCG; cg++) {
#pragma unroll
            for (int r = 0; r < 4; r++) {
                int co = cg * 16 + q * 4 + r;
                float v = softplus_f(acc[rr][cg][r] + bias[co_base + co]);
                outb[(size_t)co * HWp + y * W + x0 + lx] = v;
                if (SUMS) { s1l[cg][r] += v; s2l[cg][r] += v * v; }
            }
        }
    }
    if (SUMS) {
#pragma unroll
        for (int cg = 0; cg < NCG; cg++)
#pragma unroll
            for (int r = 0; r < 4; r++) {
                float a1 = s1l[cg][r], a2 = s2l[cg][r];
#pragma unroll
                for (int mask = 1; mask < 16; mask <<= 1) {
                    a1 += __shfl_xor(a1, mask);
                    a2 += __shfl_xor(a2, mask);
                }
                if (lx == 0) {
                    int co = cg * 16 + q * 4 + r;
                    atomicAdd(&shs[2 * co], a1);
                    atomicAdd(&shs[2 * co + 1], a2);
                }
            }
        __syncthreads();
        for (int c = tid; c < 2 * NCG * 16; c += 256)
            atomicAdd(&osum[(size_t)b * 2 * NCG * 16 + c], shs[c]);
    }
}

// bilinear 2x upsample of concat(x, v0): out ycat (B,256,128,128) fp32
__global__ __launch_bounds__(256) void upsample_kernel(const float* __restrict__ x,
                                                       const float* __restrict__ v0,
                                                       float* __restrict__ ycat) {
    size_t idx = (size_t)blockIdx.x * 256 + threadIdx.x;
    int oxy = (int)(idx & (size_t)(P2 - 1));
    int ox = oxy & 127, oy = oxy >> 7;
    int cbc = (int)(idx >> 14);
    int c = cbc & 255, b = cbc >> 8;
    const float* src = (c < 128 ? x : v0) + (size_t)(b * 128 + (c & 127)) * P1;
    int my = oy >> 1, mx = ox >> 1;
    int iy0 = (oy & 1) ? my : my - 1;
    float wy0 = (oy & 1) ? 0.75f : 0.25f;
    int ix0 = (ox & 1) ? mx : mx - 1;
    float wx0 = (ox & 1) ? 0.75f : 0.25f;
    int iy1 = min(iy0 + 1, H1 - 1); iy0 = max(iy0, 0);
    int ix1 = min(ix0 + 1, W1 - 1); ix0 = max(ix0, 0);
    float wy1 = 1.f - wy0, wx1 = 1.f - wx0;
    float v = wy0 * (wx0 * src[iy0 * W1 + ix0] + wx1 * src[iy0 * W1 + ix1])
            + wy1 * (wx0 * src[iy1 * W1 + ix0] + wx1 * src[iy1 * W1 + ix1]);
    ycat[idx] = v;
}

// 1x1 conv 384->192, bf16 MFMA, softplus, fused output sums. grid (P2/64, B).
__global__ __launch_bounds__(256) void conv1x1_mfma(
    const float* __restrict__ ycat, const float* __restrict__ skip,
    const short* __restrict__ wq, const float* __restrict__ bias,
    float* __restrict__ out, float* __restrict__ osum)
{
    __shared__ short xs[64 * 40];
    const int tid = threadIdx.x;
    const int wave = tid >> 6, lane = tid & 63;
    const int lx = lane & 15, q = lane >> 4;
    const int p0 = blockIdx.x * 64;
    const int b = blockIdx.y;

    f32x4 acc[3][4];
#pragma unroll
    for (int cg = 0; cg < 3; cg++)
#pragma unroll
        for (int pg = 0; pg < 4; pg++) acc[cg][pg] = (f32x4)(0.f);

    for (int ci0 = 0; ci0 < 384; ci0 += 32) {
        __syncthreads();
        for (int e = tid; e < 64 * 8; e += 256) {
            int px = e & 63, cq = e >> 6;
            int ci = ci0 + cq * 4;
            const float* g = (ci < 256)
                ? ycat + ((size_t)b * 256 + ci) * P2 + p0 + px
                : skip + ((size_t)b * 128 + (ci - 256)) * P2 + p0 + px;
            unsigned w0 = f2bf(g[0]) | (f2bf(g[(size_t)P2]) << 16);
            unsigned w1 = f2bf(g[(size_t)2 * P2]) | (f2bf(g[(size_t)3 * P2]) << 16);
            *(int2*)(&xs[px * 40 + cq * 4]) = make_int2((int)w0, (int)w1);
        }
        __syncthreads();
        const short* wl = wq + (size_t)(wave * 48 + lx) * 384 + ci0 + q * 8;
        short8 a[3];
#pragma unroll
        for (int cg = 0; cg < 3; cg++)
            a[cg] = *(const short8*)(wl + (size_t)cg * 16 * 384);
#pragma unroll
        for (int pg = 0; pg < 4; pg++) {
            short8 bfr = *(const short8*)(&xs[(pg * 16 + lx) * 40 + q * 8]);
#pragma unroll
            for (int cg = 0; cg < 3; cg++)
                acc[cg][pg] = __builtin_amdgcn_mfma_f32_16x16x32_bf16(
                    a[cg], bfr, acc[cg][pg], 0, 0, 0);
        }
    }

#pragma unroll
    for (int cg = 0; cg < 3; cg++) {
#pragma unroll
        for (int r = 0; r < 4; r++) {
            int co = wave * 48 + cg * 16 + q * 4 + r;
            float bi = bias[co];
            float s1 = 0.f, s2 = 0.f;
#pragma unroll
            for (int pg = 0; pg < 4; pg++) {
                float v = softplus_f(acc[cg][pg][r] + bi);
                out[((size_t)b * CS + co) * P2 + p0 + pg * 16 + lx] = v;
                s1 += v; s2 += v * v;
            }
#pragma unroll
            for (int mask = 1; mask < 16; mask <<= 1) {
                s1 += __shfl_xor(s1, mask);
                s2 += __shfl_xor(s2, mask);
            }
            if (lx == 0) {
                atomicAdd(&osum[((size_t)b * CS + co) * 2], s1);
                atomicAdd(&osum[((size_t)b * CS + co) * 2 + 1], s2);
            }
        }
    }
}

// T[a-half] = S_a + ca1*S_b + ca2*Gx ; T[b-half] = S_b + cb*Gp ; fused T sums.
// grid (P2/1024, 96, B), float4 per thread.
__global__ __launch_bounds__(256) void combine_kernel(
    const float* __restrict__ S, const float* __restrict__ Gx,
    const float* __restrict__ Gp, float* __restrict__ T,
    float* __restrict__ osum, float ca1, float ca2, float cb)
{
    int p4 = blockIdx.x * 256 + threadIdx.x;
    int ch = blockIdx.y, b = blockIdx.z;
    size_t ia4 = (((size_t)b * CS + ch) * P2) / 4 + p4;
    size_t ib4 = ia4 + (size_t)CH * P2 / 4;
    size_t ig4 = (((size_t)b * CH + ch) * P2) / 4 + p4;
    float4 sa = ((const float4*)S)[ia4];
    float4 sb = ((const float4*)S)[ib4];
    float4 gx = ((const float4*)Gx)[ig4];
    float4 gp = ((const float4*)Gp)[ig4];
    float4 ta, tb;
    ta.x = sa.x + ca1 * sb.x + ca2 * gx.x; tb.x = sb.x + cb * gp.x;
    ta.y = sa.y + ca1 * sb.y + ca2 * gx.y; tb.y = sb.y + cb * gp.y;
    ta.z = sa.z + ca1 * sb.z + ca2 * gx.z; tb.z = sb.z + cb * gp.z;
    ta.w = sa.w + ca1 * sb.w + ca2 * gx.w; tb.w = sb.w + cb * gp.w;
    ((float4*)T)[ia4] = ta;
    ((float4*)T)[ib4] = tb;

    float v0 = ta.x + ta.y + ta.z + ta.w;
    float v1 = ta.x*ta.x + ta.y*ta.y + ta.z*ta.z + ta.w*ta.w;
    float v2 = tb.x + tb.y + tb.z + tb.w;
    float v3 = tb.x*tb.x + tb.y*tb.y + tb.z*tb.z + tb.w*tb.w;
#pragma unroll
    for (int mask = 1; mask < 64; mask <<= 1) {
        v0 += __shfl_xor(v0, mask); v1 += __shfl_xor(v1, mask);
        v2 += __shfl_xor(v2, mask); v3 += __shfl_xor(v3, mask);
    }
    __shared__ float red[4][4];
    int wave = threadIdx.x >> 6;
    if ((threadIdx.x & 63) == 0) {
        red[wave][0] = v0; red[wave][1] = v1; red[wave][2] = v2; red[wave][3] = v3;
    }
    __syncthreads();
    if (threadIdx.x == 0) {
        float r0 = red[0][0] + red[1][0] + red[2][0] + red[3][0];
        float r1 = red[0][1] + red[1][1] + red[2][1] + red[3][1];
        float r2 = red[0][2] + red[1][2] + red[2][2] + red[3][2];
        float r3 = red[0][3] + red[1][3] + red[2][3] + red[3][3];
        atomicAdd(&osum[((size_t)b * CS + ch) * 2], r0);
        atomicAdd(&osum[((size_t)b * CS + ch) * 2 + 1], r1);
        atomicAdd(&osum[((size_t)b * CS + ch + CH) * 2], r2);
        atomicAdd(&osum[((size_t)b * CS + ch + CH) * 2 + 1], r3);
    }
}

// S_a += h*S_b + h^2/6*(g1+g2+g3); S_b += h/6*(g1+2g2+2g3+g4); optional fused sums.
template<bool SUMS>
__global__ __launch_bounds__(256) void final_kernel(
    float* __restrict__ S, const float* __restrict__ G1, const float* __restrict__ G2,
    const float* __restrict__ G3, const float* __restrict__ G4, float* __restrict__ osum)
{
    int p4 = blockIdx.x * 256 + threadIdx.x;
    int ch = blockIdx.y, b = blockIdx.z;
    size_t ia4 = (((size_t)b * CS + ch) * P2) / 4 + p4;
    size_t ib4 = ia4 + (size_t)CH * P2 / 4;
    size_t ig4 = (((size_t)b * CH + ch) * P2) / 4 + p4;
    float4 sa = ((const float4*)S)[ia4];
    float4 sb = ((const float4*)S)[ib4];
    float4 g1 = ((const float4*)G1)[ig4];
    float4 g2 = ((const float4*)G2)[ig4];
    float4 g3 = ((const float4*)G3)[ig4];
    float4 g4 = ((const float4*)G4)[ig4];
    const float cA = DTV * DTV / 6.0f, cB = DTV / 6.0f;
    float4 na, nb;
    na.x = sa.x + DTV * sb.x + cA * (g1.x + g2.x + g3.x);
    na.y = sa.y + DTV * sb.y + cA * (g1.y + g2.y + g3.y);
    na.z = sa.z + DTV * sb.z + cA * (g1.z + g2.z + g3.z);
    na.w = sa.w + DTV * sb.w + cA * (g1.w + g2.w + g3.w);
    nb.x = sb.x + cB * (g1.x + 2.f*g2.x + 2.f*g3.x + g4.x);
    nb.y = sb.y + cB * (g1.y + 2.f*g2.y + 2.f*g3.y + g4.y);
    nb.z = sb.z + cB * (g1.z + 2.f*g2.z + 2.f*g3.z + g4.z);
    nb.w = sb.w + cB * (g1.w + 2.f*g2.w + 2.f*g3.w + g4.w);
    ((float4*)S)[ia4] = na;
    ((float4*)S)[ib4] = nb;
    if (SUMS) {
        float v0 = na.x + na.y + na.z + na.w;
        float v1 = na.x*na.x + na.y*na.y + na.z*na.z + na.w*na.w;
        float v2 = nb.x + nb.y + nb.z + nb.w;
        float v3 = nb.x*nb.x + nb.y*nb.y + nb.z*nb.z + nb.w*nb.w;
#pragma unroll
        for (int mask = 1; mask < 64; mask <<= 1) {
            v0 += __shfl_xor(v0, mask); v1 += __shfl_xor(v1, mask);
            v2 += __shfl_xor(v2, mask); v3 += __shfl_xor(v3, mask);
        }
        __shared__ float red[4][4];
        int wave = threadIdx.x >> 6;
        if ((threadIdx.x & 63) == 0) {
            red[wave][0] = v0; red[wave][1] = v1; red[wave][2] = v2; red[wave][3] = v3;
        }
        __syncthreads();
        if (threadIdx.x == 0) {
            float r0 = red[0][0] + red[1][0] + red[2][0] + red[3][0];
            float r1 = red[0][1] + red[1][1] + red[2][1] + red[3][1];
            float r2 = red[0][2] + red[1][2] + red[2][2] + red[3][2];
            float r3 = red[0][3] + red[1][3] + red[2][3] + red[3][3];
            atomicAdd(&osum[((size_t)b * CS + ch) * 2], r0);
            atomicAdd(&osum[((size_t)b * CS + ch) * 2 + 1], r1);
            atomicAdd(&osum[((size_t)b * CS + ch + CH) * 2], r2);
            atomicAdd(&osum[((size_t)b * CS + ch + CH) * 2 + 1], r3);
        }
    }
}

extern "C" void kernel_launch(void* const* d_in, const int* in_sizes, int n_in,
                              void* d_out, int out_size, void* d_ws, size_t ws_size,
                              hipStream_t stream) {
    (void)in_sizes; (void)n_in; (void)out_size; (void)ws_size;
    const float* x    = (const float*)d_in[0];
    const float* skip = (const float*)d_in[1];
    const float* iv_w = (const float*)d_in[2];
    const float* iv_b = (const float*)d_in[3];
    const float* up_w = (const float*)d_in[4];
    const float* up_b = (const float*)d_in[5];
    const float* f1_w = (const float*)d_in[6];
    const float* f1_b = (const float*)d_in[7];
    const float* f2_w = (const float*)d_in[8];
    const float* f2_b = (const float*)d_in[9];

    float* S = (float*)d_out;                    // B x 192 x P2 (state, in-place)
    float* ws = (float*)d_ws;
    const size_t NS = (size_t)BB * CS * P2;      // 12.58M floats
    const size_t NG = (size_t)BB * CH * P2;      // 6.29M floats
    float* T   = ws;
    float* G1  = T + NS;
    float* G2  = G1 + NG;
    float* G3  = G2 + NG;
    float* G4  = G3 + NG;
    float* U   = G4 + NG;
    float* MVS = U + NG;                         // 34 slots x 1536 floats
    short* IVQ = (short*)(MVS + (size_t)34 * 1536);
    short* F1Q = IVQ + (size_t)9 * NF * NF;
    short* F2Q = F1Q + (size_t)9 * CH * CS;
    short* UPQ = F2Q + (size_t)9 * CH * CH;
    float* YCAT = G1;                            // alias (phase A only): 16.78M <= 4*NG
    float* V0   = U;                             // alias (phase A only): 2.1M <= NG

    auto slot = [&](int i) { return MVS + (size_t)i * 1536; };

    // ---- zero MV slots + repack weights ----
    zero_kernel<<<(34 * 1536 + 255) / 256, 256, 0, stream>>>(MVS, 34 * 1536);
    repack_w_kernel<<<(NF * NF * 9 + 255) / 256, 256, 0, stream>>>(iv_w, IVQ, NF, NF);
    repack_w_kernel<<<(CH * CS * 9 + 255) / 256, 256, 0, stream>>>(f1_w, F1Q, CH, CS);
    repack_w_kernel<<<(CH * CH * 9 + 255) / 256, 256, 0, stream>>>(f2_w, F2Q, CH, CH);
    repack_w1_kernel<<<(CS * 384 + 255) / 256, 256, 0, stream>>>(up_w, UPQ, CS * 384);

    // ---- Phase A ----
    meanvar_raw_kernel<<<BB * NF, 256, 0, stream>>>(x, slot(0), P1);
    conv3x3_mfma<4, false><<<dim3(W1 / 16, H1 / 8, BB * 2), 256, 0, stream>>>(
        x, slot(0), IVQ, iv_b, V0, nullptr, NF, NF, H1, W1, NF, 0, 2);
    upsample_kernel<<<(BB * 256 * P2) / 256, 256, 0, stream>>>(x, V0, YCAT);
    conv1x1_mfma<<<dim3(P2 / 64, BB), 256, 0, stream>>>(YCAT, skip, UPQ, up_b, S, slot(1));

    // ---- RK4 ODE ----
    const float h = DTV;
    float* G[4] = {G1, G2, G3, G4};
    int sc = 2;
    float* yslot = slot(1);
    const dim3 cgrd(P2 / 1024, CH, BB);

    for (int step = 0; step < 4; step++) {
        for (int sub = 0; sub < 4; sub++) {
            const float* Y = (sub == 0) ? S : T;
            float* uslot = slot(sc++);
            conv3x3_mfma<6, true><<<dim3(W2 / 16, H2 / 8, BB), 256, 0, stream>>>(
                Y, yslot, F1Q, f1_b, U, uslot, CS, CH, H2, W2, CH, 0, 1);
            conv3x3_mfma<6, false><<<dim3(W2 / 16, H2 / 8, BB), 256, 0, stream>>>(
                U, uslot, F2Q, f2_b, G[sub], nullptr, CH, CH, H2, W2, CH, 0, 1);
            if (sub < 3) {
                float* tslot = slot(sc++);
                float ca1, ca2, cb;
                const float *Gx, *Gp;
                if (sub == 0)      { ca1 = h/2; ca2 = 0.f;     Gx = G1; Gp = G1; cb = h/2; }
                else if (sub == 1) { ca1 = h/2; ca2 = h*h/4;   Gx = G1; Gp = G2; cb = h/2; }
                else               { ca1 = h;   ca2 = h*h/2;   Gx = G2; Gp = G3; cb = h;   }
                combine_kernel<<<cgrd, 256, 0, stream>>>(S, Gx, Gp, T, tslot, ca1, ca2, cb);
                yslot = tslot;
            }
        }
        float* sslot = slot(sc++);
        if (step < 3)
            final_kernel<true><<<cgrd, 256, 0, stream>>>(S, G1, G2, G3, G4, sslot);
        else
            final_kernel<false><<<cgrd, 256, 0, stream>>>(S, G1, G2, G3, G4, sslot);
        yslot = sslot;
    }
}